// Round 6
// baseline (71.708 us; speedup 1.0000x reference)
//
#include <hip/hip_runtime.h>
#include <math.h>

#define NQ 14
#define DIM (1 << NQ)      // 16384 amplitudes
#define NT 1024            // 16 waves/block -> 4 waves/SIMD (was 2): latency hiding
#define TA 16              // amplitudes per thread (4-bit reg tile)
#define NW (NT / 64)
#define PDIM (DIM + DIM / 32)   // padded: one spare cf2 per 32

// ---- compile-time for ----
template <int J> struct IC { static constexpr int v = J; };
template <int N, typename F>
__device__ __forceinline__ void sfor(F&& f) {
    if constexpr (N > 0) { sfor<N - 1>(f); f(IC<N - 1>{}); }
}

// ---- complex amplitude as a 2-wide ext_vector (one 64-bit VGPR pair) ----
typedef float cf2 __attribute__((ext_vector_type(2)));

// ---- packed fp32 gate math (verified VOP3P asm) ----
__device__ __forceinline__ cf2 pk_mul_s_swapneg(cf2 cs, cf2 a) {  // s * (a.y, -a.x)
    cf2 t;
    asm("v_pk_mul_f32 %0, %1, %2 op_sel:[1,1] op_sel_hi:[1,0] neg_hi:[0,1]"
        : "=v"(t) : "v"(cs), "v"(a));
    return t;
}
__device__ __forceinline__ cf2 pk_fma_c(cf2 cs, cf2 a, cf2 b) {   // c*a + b
    cf2 d;
    asm("v_pk_fma_f32 %0, %1, %2, %3 op_sel:[0,0,0] op_sel_hi:[0,1,1]"
        : "=v"(d) : "v"(cs), "v"(a), "v"(b));
    return d;
}

// ---- state: 16 INDEPENDENT cf2 SSA values ----
struct St {
    cf2 a0, a1, a2, a3, a4, a5, a6, a7, a8, a9, a10, a11, a12, a13, a14, a15;
};
template <int J> __device__ __forceinline__ cf2& amp(St& s);
#define AMP_GET(J) template <> __device__ __forceinline__ cf2& amp<J>(St& s) { return s.a##J; }
AMP_GET(0)  AMP_GET(1)  AMP_GET(2)  AMP_GET(3)  AMP_GET(4)  AMP_GET(5)  AMP_GET(6)  AMP_GET(7)
AMP_GET(8)  AMP_GET(9)  AMP_GET(10) AMP_GET(11) AMP_GET(12) AMP_GET(13) AMP_GET(14) AMP_GET(15)

// ---- additive padded layout: phys(idx) = idx + (idx>>5) ----
__host__ __device__ constexpr int pad(int idx) { return idx + (idx >> 5); }

// 4-reg-bit tile with explicit positions for reg bits j0..j3 (P0..P3) and
// tid bits t0..t9 (Q0..Q9). qubit q lives at bit position 13-q.
template <int P0, int P1, int P2, int P3,
          int Q0, int Q1, int Q2, int Q3, int Q4, int Q5, int Q6, int Q7, int Q8, int Q9>
struct Tile4Q {
    static __device__ __forceinline__ int base_idx(int t) {
        return (((t >> 0) & 1) << Q0) | (((t >> 1) & 1) << Q1) | (((t >> 2) & 1) << Q2) |
               (((t >> 3) & 1) << Q3) | (((t >> 4) & 1) << Q4) | (((t >> 5) & 1) << Q5) |
               (((t >> 6) & 1) << Q6) | (((t >> 7) & 1) << Q7) | (((t >> 8) & 1) << Q8) |
               (((t >> 9) & 1) << Q9);
    }
    static constexpr int off(int j) {
        return ((j & 1) << P0) | (((j >> 1) & 1) << P1) | (((j >> 2) & 1) << P2) |
               (((j >> 3) & 1) << P3);
    }
    static constexpr int poff(int j) { return pad(off(j)); }
};

// P1: reg j0..j3 = pos 10,11,12,13 (q3,q2,q1,q0); t0=pos9(q4) xor1,
//     t1=pos8(q5) xor2; t2..t9 = pos0..7 (q13,q12,q11,q10,q9,q8,q7,q6).
using TP1 = Tile4Q<10, 11, 12, 13,  9, 8, 0, 1, 2, 3, 4, 5, 6, 7>;
// P2: reg j0..j3 = pos 4,5,6,7 (q9,q8,q7,q6); t0=pos3(q10) xor1,
//     t1=pos8(q5) xor2; t2..t9 = pos 0,1,2,9,10,11,12,13.
using TP2 = Tile4Q<4, 5, 6, 7,  3, 8, 0, 1, 2, 9, 10, 11, 12, 13>;
// P3: reg j0..j3 = pos 13,0,1,2 (q0,q13,q12,q11); t0=pos3(q10) xor1;
//     t1..t9 = pos 4..12 (q9,q8,q7,q6,q5,q4,q3,q2,q1).
using TP3 = Tile4Q<13, 0, 1, 2,  3, 4, 5, 6, 7, 8, 9, 10, 11, 12>;

// Loads pair-interleaved (0,8,1,9,...) so the first gate (pairs j,j^8) can
// start after 2 returns.
template <class T>
__device__ __forceinline__ void load_tile_fold(const cf2* s, int pbLo, int pbHi, St& st) {
    sfor<TA>([&](auto jc) {
        constexpr int j0 = decltype(jc)::v;
        constexpr int j = (j0 >> 1) | ((j0 & 1) << 3);
        amp<j>(st) = s[((j & 8) ? pbHi : pbLo) + T::poff(j)];
    });
}
template <class T>
__device__ __forceinline__ void store_tile(cf2* s, int pb, St& st) {
    sfor<TA>([&](auto jc) {
        constexpr int j = decltype(jc)::v;
        s[pb + T::poff(j)] = amp<j>(st);
    });
}

// RX: [[c,-is],[-is,c]] on reg bit LB
template <int LB>
__device__ __forceinline__ void g_rx(St& st, cf2 cs) {
    sfor<TA>([&](auto jc) {
        constexpr int j = decltype(jc)::v;
        if constexpr (!(j & (1 << LB))) {
            constexpr int k = j | (1 << LB);
            cf2 aj = amp<j>(st), ak = amp<k>(st);
            amp<j>(st) = pk_fma_c(cs, aj, pk_mul_s_swapneg(cs, ak));
            amp<k>(st) = pk_fma_c(cs, ak, pk_mul_s_swapneg(cs, aj));
        }
    });
}
// LANE-wire RX via DPP quad_perm (xor1: 0xB1, xor2: 0x4E). RX is symmetric:
// out = c*a - i*s*partner on BOTH sides.
template <int CTRL>
__device__ __forceinline__ void g_rx_lane_dpp(St& st, cf2 cs) {
    sfor<TA>([&](auto jc) {
        constexpr int j = decltype(jc)::v;
        cf2 a = amp<j>(st);
        int px = __builtin_amdgcn_update_dpp(__float_as_int(a.x), __float_as_int(a.x),
                                             CTRL, 0xF, 0xF, false);
        int py = __builtin_amdgcn_update_dpp(__float_as_int(a.y), __float_as_int(a.y),
                                             CTRL, 0xF, 0xF, false);
        cf2 p; p.x = __int_as_float(px); p.y = __int_as_float(py);
        amp<j>(st) = pk_fma_c(cs, a, pk_mul_s_swapneg(cs, p));
    });
}
// CNOT both-reg: pure SSA rename (free)
template <int LC, int LT>
__device__ __forceinline__ void g_cnot(St& st) {
    sfor<TA>([&](auto jc) {
        constexpr int j = decltype(jc)::v;
        if constexpr (((j >> LC) & 1) && !((j >> LT) & 1)) {
            constexpr int k = j | (1 << LT);
            cf2 t = amp<j>(st);
            amp<j>(st) = amp<k>(st);
            amp<k>(st) = t;
        }
    });
}
// CNOT ctrl = reg bit CB (compile-time), target = lane (DPP CTRL):
// amps with ctrl=1 exchange with the lane partner — unconditional DPP mov.
template <int CTRL, int CB>
__device__ __forceinline__ void g_cnot_dppmov(St& st) {
    sfor<TA>([&](auto jc) {
        constexpr int j = decltype(jc)::v;
        if constexpr ((j >> CB) & 1) {
            cf2 a = amp<j>(st);
            int px = __builtin_amdgcn_update_dpp(__float_as_int(a.x), __float_as_int(a.x),
                                                 CTRL, 0xF, 0xF, false);
            int py = __builtin_amdgcn_update_dpp(__float_as_int(a.y), __float_as_int(a.y),
                                                 CTRL, 0xF, 0xF, false);
            cf2 p; p.x = __int_as_float(px); p.y = __int_as_float(py);
            amp<j>(st) = p;
        }
    });
}
// CNOT ctrl = runtime lane bit, target = lane (DPP CTRL): exchange + cndmask.
// (ctrl bit must be preserved by the exchange: xor2 preserves lane bit 0.)
template <int CTRL>
__device__ __forceinline__ void g_cnot_cnd(St& st, bool ctrl) {
    sfor<TA>([&](auto jc) {
        constexpr int j = decltype(jc)::v;
        cf2 a = amp<j>(st);
        int px = __builtin_amdgcn_update_dpp(__float_as_int(a.x), __float_as_int(a.x),
                                             CTRL, 0xF, 0xF, false);
        int py = __builtin_amdgcn_update_dpp(__float_as_int(a.y), __float_as_int(a.y),
                                             CTRL, 0xF, 0xF, false);
        cf2 p; p.x = __int_as_float(px); p.y = __int_as_float(py);
        amp<j>(st) = ctrl ? p : a;
    });
}

// ---- complex helpers for the analytic layer-0 closed form ----
__device__ __forceinline__ cf2 cmul(cf2 a, cf2 b) {
    cf2 r; r.x = a.x * b.x - a.y * b.y; r.y = a.x * b.y + a.y * b.x; return r;
}
// v = RX(w)RY(a)|0>, component b:  v[0]=(cx*cy, -sx*sy), v[1]=(cx*sy, -sx*cy)
__device__ __forceinline__ cf2 v_of(cf2 ry, cf2 rx, int b) {
    cf2 r;
    r.x = b ? rx.x * ry.y : rx.x * ry.x;
    r.y = b ? -(rx.y * ry.x) : -(rx.y * ry.y);
    return r;
}

// ---- DPP wave-sum (pure VALU; total lands in lane 63) ----
template <int CTRL, int RM>
__device__ __forceinline__ float dpp_add_step(float v) {
    int t = __builtin_amdgcn_update_dpp(0, __float_as_int(v), CTRL, RM, 0xF, true);
    return v + __int_as_float(t);
}
__device__ __forceinline__ float wave_red(float v) {
    v = dpp_add_step<0x111, 0xF>(v);  // row_shr:1
    v = dpp_add_step<0x112, 0xF>(v);  // row_shr:2
    v = dpp_add_step<0x114, 0xF>(v);  // row_shr:4
    v = dpp_add_step<0x118, 0xF>(v);  // row_shr:8
    v = dpp_add_step<0x142, 0xA>(v);  // row_bcast:15
    v = dpp_add_step<0x143, 0xC>(v);  // row_bcast:31
    return v;
}

// ============================================================================
// NT=1024 / TA=16 schedule (3 passes, 4 waves/SIMD):
//  P1: analytic L0 (embed RY + layer-0 RX + ring = XOR relabeling of a
//      product state) -> TP1 regs; L1 RX q0..3 (reg), q4 (xor1), q5 (xor2);
//      C(0,1)..(2,3) reg, C(3,4) dppmov (ctrl j0), C(4,5) cnd (ctrl t0);
//      L2 RX q1..q3 (reg), q4 (xor1).  [R2(q) needs only C1(q,q+1).] store.
//  P2: TP2; load-fold C(5,6) (ctrl q5=t1, target q6=j3, delta pad(128)=132);
//      L1 RX q6..9 (reg), q10 (xor1); L2 RX q5 (xor2); C(6,7)..(8,9) reg,
//      C(9,10) dppmov; L2 RX q6..q9 (reg). store.
//  P3: TP3; load-fold C(10,11) (ctrl q10=t0, target q11=j3, delta pad(4)=4);
//      L1 RX q11,q12,q13 (reg); L2 RX q10 (xor1); C(11,12),(12,13) reg,
//      C(13,0) reg (q13=j1, q0=j0 both in-reg!); L2 RX q11..q13,q0 (reg).
//      L2 ring folded into epilogue prefix-parity signs. no store.
// ============================================================================
__global__ void __launch_bounds__(NT) qsim_kernel(const float* __restrict__ x,
                                                  const float* __restrict__ w,
                                                  float* __restrict__ out) {
    __shared__ cf2 sSt[PDIM];            // ~132 KB padded
    __shared__ cf2 sCS[56];              // (cos,sin): [0..13]=RY embed, 14+l*14+q = RX
    __shared__ float sRed[NW][NQ];

    const int tid = threadIdx.x;
    const int b = blockIdx.x;

    if (tid < 56) {
        float f;
        if (tid < 14) {
            // angle = tanh(x)*pi/2 rad = tanh(x)*0.25 revolutions (|f|<0.25)
            float v = x[b * NQ + tid];
            float e = __builtin_amdgcn_exp2f(v * 2.8853900817779268f);  // e^(2v)
            float t = fmaf(-2.f, __builtin_amdgcn_rcpf(e + 1.f), 1.f);  // tanh(v)
            f = t * 0.25f;
        } else {
            // angle = w*0.5 rad = w/(4*pi) revolutions, w in [0,2pi) -> f<0.5
            f = w[tid - 14] * 0.07957747154594767f;
        }
        cf2 v2; v2.x = __builtin_amdgcn_cosf(f); v2.y = __builtin_amdgcn_sinf(f);
        sCS[tid] = v2;
    }

    const int pb1 = pad(TP1::base_idx(tid));
    const int pb2 = pad(TP2::base_idx(tid));
    const int pb3 = pad(TP3::base_idx(tid));
    // P2 fold: target q6 = pos7 -> delta pad(128)=132; ctrl q5 = t1
    const int d2 = ((tid >> 1) & 1) ? 132 : 0;
    const int pb2lo = pb2 + d2, pb2hi = pb2 - d2;
    // P3 fold: target q11 = pos2 -> delta pad(4)=4; ctrl q10 = t0
    const int d3 = (tid & 1) ? 4 : 0;
    const int pb3lo = pb3 + d3, pb3hi = pb3 - d3;

    __syncthreads();

    St st;

    // ===== P1: analytic layer-0 init of TP1 + L1 q0-5 + L2 q1-4 =====
    {
        const int t0 = tid & 1,        t1 = (tid >> 1) & 1, t2 = (tid >> 2) & 1,
                  t3 = (tid >> 3) & 1, t4 = (tid >> 4) & 1, t5 = (tid >> 5) & 1,
                  t6 = (tid >> 6) & 1, t7 = (tid >> 7) & 1, t8 = (tid >> 8) & 1,
                  t9 = (tid >> 9) & 1;
        // c-bits (TP1): c0=j3 c1=j2 c2=j1 c3=j0 c4=t0 c5=t1 c6=t9 c7=t8
        //               c8=t7 c9=t6 c10=t5 c11=t4 c12=t3 c13=t2
        // b = M^{-1}c: b0=c0^c13, b1=c1^c0^c13, bk=ck^c(k-1) (k>=2)
        // Thread-uniform factors: b5=t1^t0 b6=t9^t1 b7=t8^t9 b8=t7^t8
        //   b9=t6^t7 b10=t5^t6 b11=t4^t5 b12=t3^t4 b13=t2^t3
        cf2 Pref = v_of(sCS[5], sCS[19], t1 ^ t0);
        Pref = cmul(Pref, v_of(sCS[6],  sCS[20], t9 ^ t1));
        Pref = cmul(Pref, v_of(sCS[7],  sCS[21], t8 ^ t9));
        Pref = cmul(Pref, v_of(sCS[8],  sCS[22], t7 ^ t8));
        Pref = cmul(Pref, v_of(sCS[9],  sCS[23], t6 ^ t7));
        Pref = cmul(Pref, v_of(sCS[10], sCS[24], t5 ^ t6));
        Pref = cmul(Pref, v_of(sCS[11], sCS[25], t4 ^ t5));
        Pref = cmul(Pref, v_of(sCS[12], sCS[26], t3 ^ t4));
        Pref = cmul(Pref, v_of(sCS[13], sCS[27], t2 ^ t3));
        // Reg-dependent: b0=j3^t2 b1=j2^j3^t2 b2=j1^j2 b3=j0^j1 b4=t0^j0
        cf2 w0[2] = { v_of(sCS[0], sCS[14], t2), v_of(sCS[0], sCS[14], 1 ^ t2) };
        cf2 w1[2] = { v_of(sCS[1], sCS[15], t2), v_of(sCS[1], sCS[15], 1 ^ t2) };
        cf2 v2a[2] = { v_of(sCS[2], sCS[16], 0), v_of(sCS[2], sCS[16], 1) };
        cf2 v3a[2] = { v_of(sCS[3], sCS[17], 0), v_of(sCS[3], sCS[17], 1) };
        cf2 w4[2] = { v_of(sCS[4], sCS[18], t0), v_of(sCS[4], sCS[18], 1 ^ t0) };
        // u[(j1<<1)|j0] = v3a[j0^j1] * w4[j0]
        cf2 u[4] = { cmul(v3a[0], w4[0]), cmul(v3a[1], w4[1]),
                     cmul(v3a[1], w4[0]), cmul(v3a[0], w4[1]) };
        cf2 tA[2], tB[4], tC[8];
        sfor<2>([&](auto ic) {
            constexpr int i = decltype(ic)::v;
            tA[i] = cmul(Pref, w0[i]);
        });
        sfor<4>([&](auto ic) {
            constexpr int i = decltype(ic)::v;           // i = (j3<<1)|j2
            constexpr int j3b = i >> 1, j2b = i & 1;
            tB[i] = cmul(tA[j3b], w1[j2b ^ j3b]);
        });
        sfor<8>([&](auto ic) {
            constexpr int i = decltype(ic)::v;           // i = (j3,j2,j1)
            constexpr int j2b = (i >> 1) & 1, j1b = i & 1;
            tC[i] = cmul(tB[i >> 1], v2a[j1b ^ j2b]);
        });
        sfor<TA>([&](auto jc) {
            constexpr int j = decltype(jc)::v;
            amp<j>(st) = cmul(tC[j >> 1], u[j & 3]);
        });

        // L1 RX q0..q3 (reg j3..j0), q4 (xor1), q5 (xor2)
        g_rx<3>(st, sCS[28 + 0]); g_rx<2>(st, sCS[28 + 1]);
        g_rx<1>(st, sCS[28 + 2]); g_rx<0>(st, sCS[28 + 3]);
        g_rx_lane_dpp<0xB1>(st, sCS[28 + 4]);
        g_rx_lane_dpp<0x4E>(st, sCS[28 + 5]);
        // ring: C(0,1) C(1,2) C(2,3) reg; C(3,4) dppmov; C(4,5) cnd
        g_cnot<3, 2>(st); g_cnot<2, 1>(st); g_cnot<1, 0>(st);
        g_cnot_dppmov<0xB1, 0>(st);
        g_cnot_cnd<0x4E>(st, (bool)(tid & 1));
        // L2 RX q1,q2,q3 (reg), q4 (xor1)
        g_rx<2>(st, sCS[42 + 1]); g_rx<1>(st, sCS[42 + 2]); g_rx<0>(st, sCS[42 + 3]);
        g_rx_lane_dpp<0xB1>(st, sCS[42 + 4]);
        store_tile<TP1>(sSt, pb1, st);
    }
    __syncthreads();

    // ===== P2: fold C(5,6); L1 q6-10; L2 q5-9 =====
    {
        load_tile_fold<TP2>(sSt, pb2lo, pb2hi, st);
        g_rx<3>(st, sCS[28 + 6]); g_rx<2>(st, sCS[28 + 7]);
        g_rx<1>(st, sCS[28 + 8]); g_rx<0>(st, sCS[28 + 9]);
        g_rx_lane_dpp<0xB1>(st, sCS[28 + 10]);   // L1 q10 (t0)
        g_rx_lane_dpp<0x4E>(st, sCS[42 + 5]);    // L2 q5 (t1; needs C(4,5),C(5,6) ok)
        g_cnot<3, 2>(st); g_cnot<2, 1>(st); g_cnot<1, 0>(st);  // C(6,7)(7,8)(8,9)
        g_cnot_dppmov<0xB1, 0>(st);              // C(9,10): ctrl q9=j0, target t0
        g_rx<3>(st, sCS[42 + 6]); g_rx<2>(st, sCS[42 + 7]);
        g_rx<1>(st, sCS[42 + 8]); g_rx<0>(st, sCS[42 + 9]);
        store_tile<TP2>(sSt, pb2, st);
    }
    __syncthreads();

    // ===== P3: fold C(10,11); L1 q11-13 + C(13,0) in-reg; L2 q10-13,q0 =====
    {
        load_tile_fold<TP3>(sSt, pb3lo, pb3hi, st);
        g_rx<3>(st, sCS[28 + 11]); g_rx<2>(st, sCS[28 + 12]); g_rx<1>(st, sCS[28 + 13]);
        g_rx_lane_dpp<0xB1>(st, sCS[42 + 10]);   // L2 q10 (t0; needs C(9,10),C(10,11) ok)
        g_cnot<3, 2>(st);  // C(11,12)
        g_cnot<2, 1>(st);  // C(12,13)
        g_cnot<1, 0>(st);  // C(13,0): ctrl q13=j1, target q0=j0 — plain rename
        g_rx<3>(st, sCS[42 + 11]); g_rx<2>(st, sCS[42 + 12]);
        g_rx<1>(st, sCS[42 + 13]); g_rx<0>(st, sCS[42 + 0]);
    }

    // ====== epilogue: L2 ring folded as prefix-parity signs ======
    // (Mb)_0 = b1^..^b13; (Mb)_k = b0^..^bk (k>=1).
    // P3 bit map: q0=j0 q13=j1 q12=j2 q11=j3; q10=t0 q9=t1 q8=t2 q7=t3 q6=t4
    //             q5=t5 (lanes); q4=t6 q3=t7 q2=t8 q1=t9 (wave).
    // Reg classes: A0={j3,j2,j1}(Z0); A1={j0}(Z1..10); A2={j0,j3}(Z11);
    //              A3={j0,j3,j2}(Z12); A4={j0,j3,j2,j1}(Z13).
    {
        float A0 = 0.f, A1 = 0.f, A2 = 0.f, A3 = 0.f, A4 = 0.f;
        sfor<TA>([&](auto jc) {
            constexpr int j = decltype(jc)::v;
            cf2 v = amp<j>(st);
            float pj = v.x * v.x + v.y * v.y;
            constexpr int j0 = j & 1, j1 = (j >> 1) & 1, j2 = (j >> 2) & 1,
                          j3 = (j >> 3) & 1;
            constexpr int s0 = j3 ^ j2 ^ j1;
            constexpr int s1 = j0;
            constexpr int s2 = j0 ^ j3;
            constexpr int s3 = s2 ^ j2;
            constexpr int s4 = s3 ^ j1;
            A0 += s0 ? -pj : pj;
            A1 += s1 ? -pj : pj;
            A2 += s2 ? -pj : pj;
            A3 += s3 ? -pj : pj;
            A4 += s4 ? -pj : pj;
        });
        const int t0 = tid & 1,        t1 = (tid >> 1) & 1, t2 = (tid >> 2) & 1,
                  t3 = (tid >> 3) & 1, t4 = (tid >> 4) & 1, t5 = (tid >> 5) & 1,
                  t6 = (tid >> 6) & 1, t7 = (tid >> 7) & 1, t8 = (tid >> 8) & 1,
                  t9 = (tid >> 9) & 1;
        // lane prefix parities (q5..q10 live on t5..t0)
        const int L5 = t5, L6 = L5 ^ t4, L7 = L6 ^ t3, L8 = L7 ^ t2, L9 = L8 ^ t1;
        const int LA = L9 ^ t0;                          // q5..q10 all
        // wave prefix parities (q1..q4 on t9..t6)
        const int W1 = t9, W2 = W1 ^ t8, W3 = W2 ^ t7, W4 = W3 ^ t6;

        float RZ0 = wave_red(LA ? -A0 : A0);
        float R14 = wave_red(A1);
        float R5  = wave_red(L5 ? -A1 : A1);
        float R6  = wave_red(L6 ? -A1 : A1);
        float R7  = wave_red(L7 ? -A1 : A1);
        float R8  = wave_red(L8 ? -A1 : A1);
        float R9  = wave_red(L9 ? -A1 : A1);
        float R10 = wave_red(LA ? -A1 : A1);
        float R11 = wave_red(LA ? -A2 : A2);
        float R12 = wave_red(LA ? -A3 : A3);
        float R13 = wave_red(LA ? -A4 : A4);

        const int wv = tid >> 6, ln = tid & 63;
        if (ln == 63) {
            sRed[wv][0]  = W4 ? -RZ0 : RZ0;
            sRed[wv][1]  = W1 ? -R14 : R14;
            sRed[wv][2]  = W2 ? -R14 : R14;
            sRed[wv][3]  = W3 ? -R14 : R14;
            sRed[wv][4]  = W4 ? -R14 : R14;
            sRed[wv][5]  = W4 ? -R5  : R5;
            sRed[wv][6]  = W4 ? -R6  : R6;
            sRed[wv][7]  = W4 ? -R7  : R7;
            sRed[wv][8]  = W4 ? -R8  : R8;
            sRed[wv][9]  = W4 ? -R9  : R9;
            sRed[wv][10] = W4 ? -R10 : R10;
            sRed[wv][11] = W4 ? -R11 : R11;
            sRed[wv][12] = W4 ? -R12 : R12;
            sRed[wv][13] = W4 ? -R13 : R13;
        }
        __syncthreads();
        if (tid < NQ) {
            float acc = 0.f;
#pragma unroll
            for (int k = 0; k < NW; ++k) acc += sRed[k][tid];
            out[b * NQ + tid] = acc;
        }
    }
}

extern "C" void kernel_launch(void* const* d_in, const int* in_sizes, int n_in,
                              void* d_out, int out_size, void* d_ws, size_t ws_size,
                              hipStream_t stream) {
    const float* x = (const float*)d_in[0];   // (256, 14) float32
    const float* w = (const float*)d_in[1];   // (3, 14) float32
    float* out = (float*)d_out;               // (256, 14) float32
    qsim_kernel<<<256, NT, 0, stream>>>(x, w, out);
}

// Round 7
// 67.818 us; speedup vs baseline: 1.0574x; 1.0574x over previous
//
#include <hip/hip_runtime.h>
#include <math.h>

#define NQ 14
#define DIM (1 << NQ)      // 16384 amplitudes
#define NT 512             // 8 waves per block; ~132 KB LDS -> 1 block/CU
#define TA 32              // amplitudes per thread (5-bit tile)
#define NW (NT / 64)
#define PDIM (DIM + DIM / 32)   // padded: one spare cf2 per 32

// ---- compile-time for ----
template <int J> struct IC { static constexpr int v = J; };
template <int N, typename F>
__device__ __forceinline__ void sfor(F&& f) {
    if constexpr (N > 0) { sfor<N - 1>(f); f(IC<N - 1>{}); }
}

// ---- complex amplitude as a 2-wide ext_vector (one 64-bit VGPR pair) ----
typedef float cf2 __attribute__((ext_vector_type(2)));

// ---- packed fp32 gate math (r14/r15-verified VOP3P asm). cs = (cos,sin) in
// ONE register pair; op_sel broadcasts the needed half. ----
__device__ __forceinline__ cf2 pk_mul_s_swapneg(cf2 cs, cf2 a) {  // s * (a.y, -a.x)
    cf2 t;
    asm("v_pk_mul_f32 %0, %1, %2 op_sel:[1,1] op_sel_hi:[1,0] neg_hi:[0,1]"
        : "=v"(t) : "v"(cs), "v"(a));
    return t;
}
__device__ __forceinline__ cf2 pk_fma_c(cf2 cs, cf2 a, cf2 b) {   // c*a + b
    cf2 d;
    asm("v_pk_fma_f32 %0, %1, %2, %3 op_sel:[0,0,0] op_sel_hi:[0,1,1]"
        : "=v"(d) : "v"(cs), "v"(a), "v"(b));
    return d;
}

// ---- state: 32 INDEPENDENT cf2 SSA values ----
struct St {
    cf2 a0, a1, a2, a3, a4, a5, a6, a7, a8, a9, a10, a11, a12, a13, a14, a15,
        a16, a17, a18, a19, a20, a21, a22, a23, a24, a25, a26, a27, a28, a29, a30, a31;
};
template <int J> __device__ __forceinline__ cf2& amp(St& s);
#define AMP_GET(J) template <> __device__ __forceinline__ cf2& amp<J>(St& s) { return s.a##J; }
AMP_GET(0)  AMP_GET(1)  AMP_GET(2)  AMP_GET(3)  AMP_GET(4)  AMP_GET(5)  AMP_GET(6)  AMP_GET(7)
AMP_GET(8)  AMP_GET(9)  AMP_GET(10) AMP_GET(11) AMP_GET(12) AMP_GET(13) AMP_GET(14) AMP_GET(15)
AMP_GET(16) AMP_GET(17) AMP_GET(18) AMP_GET(19) AMP_GET(20) AMP_GET(21) AMP_GET(22) AMP_GET(23)
AMP_GET(24) AMP_GET(25) AMP_GET(26) AMP_GET(27) AMP_GET(28) AMP_GET(29) AMP_GET(30) AMP_GET(31)

// ---- additive padded layout: phys(idx) = idx + (idx>>5); disjoint-bit sums
// split -> every LDS access = base + compile-time const. ----
__host__ __device__ constexpr int pad(int idx) { return idx + (idx >> 5); }

// Natural tile: tid bits take non-tile positions in increasing order.
template <int P0, int P1, int P2, int P3, int P4>
struct Tile5 {
    static constexpr int PMASK = (1 << P0) | (1 << P1) | (1 << P2) | (1 << P3) | (1 << P4);
    static __device__ __forceinline__ int base_idx(int t) {
        int idx = 0, tb = 0;
#pragma unroll
        for (int p = 0; p < NQ; ++p)
            if (!((PMASK >> p) & 1)) { idx |= ((t >> tb) & 1) << p; ++tb; }
        return idx;
    }
    static constexpr int off(int j) {
        return ((j & 1) << P0) | (((j >> 1) & 1) << P1) | (((j >> 2) & 1) << P2) |
               (((j >> 3) & 1) << P3) | (((j >> 4) & 1) << P4);
    }
    static constexpr int poff(int j) { return pad(off(j)); }
};
// Custom tile: explicit positions Q0..Q8 for tid bits 0..8 (lets us pin a
// chosen qubit to lane bit 0 so its gate becomes a DPP xor1 exchange).
template <int P0, int P1, int P2, int P3, int P4,
          int Q0, int Q1, int Q2, int Q3, int Q4, int Q5, int Q6, int Q7, int Q8>
struct Tile5Q {
    static __device__ __forceinline__ int base_idx(int t) {
        return (((t >> 0) & 1) << Q0) | (((t >> 1) & 1) << Q1) | (((t >> 2) & 1) << Q2) |
               (((t >> 3) & 1) << Q3) | (((t >> 4) & 1) << Q4) | (((t >> 5) & 1) << Q5) |
               (((t >> 6) & 1) << Q6) | (((t >> 7) & 1) << Q7) | (((t >> 8) & 1) << Q8);
    }
    static constexpr int off(int j) {
        return ((j & 1) << P0) | (((j >> 1) & 1) << P1) | (((j >> 2) & 1) << P2) |
               (((j >> 3) & 1) << P3) | (((j >> 4) & 1) << P4);
    }
    static constexpr int poff(int j) { return pad(off(j)); }
};

// qubit q lives at bit position 13-q.
using TT1 = Tile5<9, 10, 11, 12, 13>;  // l4..l0 = q0,q1,q2,q3,q4; t0..t8 = q13..q5
// TT2Q: reg l4..l0 = q5,q6,q7,q8,q9; t0 = q4 (pos9) -> L2 RX(q4) = DPP xor1
using TT2Q = Tile5Q<4, 5, 6, 7, 8,  9, 0, 1, 2, 3, 10, 11, 12, 13>;
using TT3 = Tile5<13, 0, 1, 2, 3>;     // l4..l0 = q10,q11,q12,q13,q0; t0=q9 t1=q8 .. t8=q1

// Folded load: l4=0 amps read from pbLo, l4=1 from pbHi (bases carry +/-delta
// when the tid ctrl bit is set) -> applies CNOT(ctrl,tile-l4) at load time.
// Issued pair-interleaved so the first (cross-l4) gate starts after 2 returns.
template <class T>
__device__ __forceinline__ void load_tile_fold(const cf2* s, int pbLo, int pbHi, St& st) {
    sfor<TA>([&](auto jc) {
        constexpr int j0 = decltype(jc)::v;
        constexpr int j = (j0 >> 1) | ((j0 & 1) << 4);
        amp<j>(st) = s[((j & 16) ? pbHi : pbLo) + T::poff(j)];
    });
}
template <class T, int HI>
__device__ __forceinline__ void store_half(cf2* s, int pb, St& st) {
    sfor<TA>([&](auto jc) {
        constexpr int j = decltype(jc)::v;
        if constexpr ((j >> 4) == HI) s[pb + T::poff(j)] = amp<j>(st);
    });
}

// RX: [[c,-is],[-is,c]]  (full-tile; used for cross-l4 gates)
template <int LB>
__device__ __forceinline__ void g_rx(St& st, cf2 cs) {
    sfor<TA>([&](auto jc) {
        constexpr int j = decltype(jc)::v;
        if constexpr (!(j & (1 << LB))) {
            constexpr int k = j | (1 << LB);
            cf2 aj = amp<j>(st), ak = amp<k>(st);
            amp<j>(st) = pk_fma_c(cs, aj, pk_mul_s_swapneg(cs, ak));
            amp<k>(st) = pk_fma_c(cs, ak, pk_mul_s_swapneg(cs, aj));
        }
    });
}
// group-restricted (l4 == HI) RX
template <int LB, int HI>
__device__ __forceinline__ void g_rx_h(St& st, cf2 cs) {
    sfor<TA>([&](auto jc) {
        constexpr int j = decltype(jc)::v;
        if constexpr (!(j & (1 << LB)) && ((j >> 4) == HI)) {
            constexpr int k = j | (1 << LB);
            cf2 aj = amp<j>(st), ak = amp<k>(st);
            amp<j>(st) = pk_fma_c(cs, aj, pk_mul_s_swapneg(cs, ak));
            amp<k>(st) = pk_fma_c(cs, ak, pk_mul_s_swapneg(cs, aj));
        }
    });
}
// LANE-wire RX via DPP quad_perm ONLY (VALU-side, free; ds_swizzle variants
// removed after r3 post-mortem: they re-enter the LDS pipe and cost a pass).
// RX is symmetric: out = c*a - i*s*partner on BOTH sides. Full tile.
template <int CTRL>
__device__ __forceinline__ void g_rx_lane_dpp(St& st, cf2 cs) {
    sfor<TA>([&](auto jc) {
        constexpr int j = decltype(jc)::v;
        cf2 a = amp<j>(st);
        int px = __builtin_amdgcn_update_dpp(__float_as_int(a.x), __float_as_int(a.x),
                                             CTRL, 0xF, 0xF, false);
        int py = __builtin_amdgcn_update_dpp(__float_as_int(a.y), __float_as_int(a.y),
                                             CTRL, 0xF, 0xF, false);
        cf2 p; p.x = __int_as_float(px); p.y = __int_as_float(py);
        amp<j>(st) = pk_fma_c(cs, a, pk_mul_s_swapneg(cs, p));
    });
}
// CNOT both-local restricted to half HI: pure SSA rename (free)
template <int LC, int LT, int HI>
__device__ __forceinline__ void g_cnot_h(St& st) {
    sfor<TA>([&](auto jc) {
        constexpr int j = decltype(jc)::v;
        if constexpr (((j >> LC) & 1) && !((j >> LT) & 1) && ((j >> 4) == HI)) {
            constexpr int k = j | (1 << LT);
            cf2 t = amp<j>(st);
            amp<j>(st) = amp<k>(st);
            amp<k>(st) = t;
        }
    });
}

// ---- complex helpers for the analytic layer-0 closed form ----
__device__ __forceinline__ cf2 cmul(cf2 a, cf2 b) {
    cf2 r; r.x = a.x * b.x - a.y * b.y; r.y = a.x * b.y + a.y * b.x; return r;
}
// v = RX(w)RY(a)|0>, component b:  v[0]=(cx*cy, -sx*sy), v[1]=(cx*sy, -sx*cy)
__device__ __forceinline__ cf2 v_of(cf2 ry, cf2 rx, int b) {
    cf2 r;
    r.x = b ? rx.x * ry.y : rx.x * ry.x;
    r.y = b ? -(rx.y * ry.x) : -(rx.y * ry.y);
    return r;
}

// ---- DPP wave-sum: canonical GCN sequence (row_shr 1/2/4/8 + row_bcast
// 15/31). Pure VALU (no LDS pipe, unlike __shfl_down's ds path). Full sum
// lands in lane 63. bound_ctrl=true -> OOB lanes contribute 0; masked rows
// get old=0 on the bcast steps. ----
template <int CTRL, int RM>
__device__ __forceinline__ float dpp_add_step(float v) {
    int t = __builtin_amdgcn_update_dpp(0, __float_as_int(v), CTRL, RM, 0xF, true);
    return v + __int_as_float(t);
}
__device__ __forceinline__ float wave_red(float v) {
    v = dpp_add_step<0x111, 0xF>(v);  // row_shr:1
    v = dpp_add_step<0x112, 0xF>(v);  // row_shr:2
    v = dpp_add_step<0x114, 0xF>(v);  // row_shr:4
    v = dpp_add_step<0x118, 0xF>(v);  // row_shr:8   (lane 15 of each row = row sum)
    v = dpp_add_step<0x142, 0xA>(v);  // row_bcast:15 -> rows 1,3
    v = dpp_add_step<0x143, 0xC>(v);  // row_bcast:31 -> rows 2,3; lane 63 = total
    return v;
}

// ============================================================================
// Schedule (3 passes — verified structural floor with verified primitives):
//  P1: analytic L0 (ring = XOR relabeling of a product state) -> TT1 regs;
//      L1 RX q0..4 + chain (q0,q1)..(q3,q4); L2 RX q1,q2,q3 (reg). store.
//  P2: TT2Q (q4 pinned to lane bit 0); load-fold L1 CNOT(q4,q5);
//      L1 RX q5..9; L2 RX q4 (DPP xor1); chains; L2 RX q5 + q6,q7,q8. store.
//  P3: load-fold L1 CNOT(q9,q10); L1 RX q10..13 + chain (..q13,q0);
//      L2 RX q9 (DPP xor1); L2 RX q10..13,q0 (reg). NO STORE: L2's CNOT ring
//      is a basis relabeling folded into the epilogue as prefix-parity signs.
//  r6 post-mortem: NT=1024/TA=16 regressed (+3.8 µs) — lane gates cost 2x
//  reg gates in VALU and displaced free reg-CNOTs; kernel is VALU-bound
//  within passes. This NT=512/TA=32 config is the verified optimum.
// ============================================================================
__global__ void __launch_bounds__(NT) qsim_kernel(const float* __restrict__ x,
                                                  const float* __restrict__ w,
                                                  float* __restrict__ out) {
    __shared__ cf2 sSt[PDIM];            // ~132 KB padded
    __shared__ cf2 sCS[56];              // (cos,sin): [0..13]=RY embed, 14+l*14+q = RX
    __shared__ float sRed[NW][NQ];

    const int tid = threadIdx.x;
    const int b = blockIdx.x;

    if (tid < 56) {
        float f;
        if (tid < 14) {
            // angle = tanh(x)*pi/2 radians = tanh(x)*0.25 revolutions
            float v = x[b * NQ + tid];
            float e = __builtin_amdgcn_exp2f(v * 2.8853900817779268f);  // e^(2v)
            float t = fmaf(-2.f, __builtin_amdgcn_rcpf(e + 1.f), 1.f);  // tanh(v)
            f = t * 0.25f;
        } else {
            // angle = w*0.5 radians = w/(4*pi) revolutions, w in [0, 2pi)
            f = w[tid - 14] * 0.07957747154594767f;
        }
        cf2 v2; v2.x = __builtin_amdgcn_cosf(f); v2.y = __builtin_amdgcn_sinf(f);
        sCS[tid] = v2;
    }

    const int pbT1 = pad(TT1::base_idx(tid));
    const int pbT2 = pad(TT2Q::base_idx(tid));
    const int pbT3 = pad(TT3::base_idx(tid));
    // fold bases: T2 target q5 = bit8 -> delta pad(256)=264; ctrl q4 = t0 (TT2Q)
    const int d2 = (tid & 1) ? 264 : 0;
    const int pbT2lo = pbT2 + d2, pbT2hi = pbT2 - d2;
    // T3 target q10 = bit3 -> delta pad(8)=8; ctrl q9 = t0 (TT3)
    const int d3 = (tid & 1) ? 8 : 0;
    const int pbT3lo = pbT3 + d3, pbT3hi = pbT3 - d3;

    __syncthreads();

    St st;

    // ===== P1: analytic layer-0 init of TT1 + L1-T1 gates + L2 q1..q3 =====
    {
        const int t0 = tid & 1,        t1 = (tid >> 1) & 1, t2 = (tid >> 2) & 1,
                  t3 = (tid >> 3) & 1, t4 = (tid >> 4) & 1, t5 = (tid >> 5) & 1,
                  t6 = (tid >> 6) & 1, t7 = (tid >> 7) & 1, t8 = (tid >> 8) & 1;
        // TT1 tid bits: c5=t8 c6=t7 c7=t6 c8=t5 c9=t4 c10=t3 c11=t2 c12=t1 c13=t0
        // b_k = c_k ^ c_{k-1}:
        const int b6 = t7 ^ t8, b7 = t6 ^ t7, b8 = t5 ^ t6, b9 = t4 ^ t5;
        const int b10 = t3 ^ t4, b11 = t2 ^ t3, b12 = t1 ^ t2, b13 = t0 ^ t1;
        cf2 Pref = v_of(sCS[6], sCS[20], b6);
        Pref = cmul(Pref, v_of(sCS[7],  sCS[21], b7));
        Pref = cmul(Pref, v_of(sCS[8],  sCS[22], b8));
        Pref = cmul(Pref, v_of(sCS[9],  sCS[23], b9));
        Pref = cmul(Pref, v_of(sCS[10], sCS[24], b10));
        Pref = cmul(Pref, v_of(sCS[11], sCS[25], b11));
        Pref = cmul(Pref, v_of(sCS[12], sCS[26], b12));
        Pref = cmul(Pref, v_of(sCS[13], sCS[27], b13));
        // Reg bits (TT1): c0=j4 c1=j3 c2=j2 c3=j1 c4=j0.
        cf2 w0[2] = { v_of(sCS[0], sCS[14], t0),     v_of(sCS[0], sCS[14], 1 ^ t0) };
        cf2 w1[2] = { v_of(sCS[1], sCS[15], t0),     v_of(sCS[1], sCS[15], 1 ^ t0) };
        cf2 v2[2] = { v_of(sCS[2], sCS[16], 0),      v_of(sCS[2], sCS[16], 1) };
        cf2 v3[2] = { v_of(sCS[3], sCS[17], 0),      v_of(sCS[3], sCS[17], 1) };
        cf2 v4[2] = { v_of(sCS[4], sCS[18], 0),      v_of(sCS[4], sCS[18], 1) };
        cf2 w5[2] = { v_of(sCS[5], sCS[19], t8),     v_of(sCS[5], sCS[19], 1 ^ t8) };
        cf2 u[4] = { cmul(v4[0], w5[0]), cmul(v4[1], w5[1]),
                     cmul(v4[1], w5[0]), cmul(v4[0], w5[1]) };
        cf2 tA[2], tB[4], tC[8], tD[16];
        sfor<2>([&](auto ic) {
            constexpr int i = decltype(ic)::v;
            tA[i] = cmul(Pref, w0[i]);
        });
        sfor<4>([&](auto ic) {
            constexpr int i = decltype(ic)::v;           // i = (j4<<1)|j3
            constexpr int j4 = i >> 1, j3 = i & 1;
            tB[i] = cmul(tA[j4], w1[j3 ^ j4]);
        });
        sfor<8>([&](auto ic) {
            constexpr int i = decltype(ic)::v;           // i = (j4,j3,j2)
            constexpr int j3 = (i >> 1) & 1, j2 = i & 1;
            tC[i] = cmul(tB[i >> 1], v2[j2 ^ j3]);
        });
        sfor<16>([&](auto ic) {
            constexpr int i = decltype(ic)::v;           // i = (j4,j3,j2,j1)
            constexpr int j2 = (i >> 1) & 1, j1 = i & 1;
            tD[i] = cmul(tC[i >> 1], v3[j1 ^ j2]);
        });
        sfor<TA>([&](auto jc) {
            constexpr int j = decltype(jc)::v;
            constexpr int j0 = j & 1, j1 = (j >> 1) & 1;
            amp<j>(st) = cmul(tD[j >> 1], u[(j1 << 1) | j0]);
        });

        // L1-T1: RX q0..q4 (l4..l0) + CNOT(q0,q1)..(q3,q4); then L2 RX q1..q3
        g_rx<4>(st, sCS[28 + 0]);
        g_rx_h<3, 0>(st, sCS[28 + 1]); g_rx_h<2, 0>(st, sCS[28 + 2]);
        g_rx_h<1, 0>(st, sCS[28 + 3]); g_rx_h<0, 0>(st, sCS[28 + 4]);
        g_cnot_h<3, 2, 0>(st); g_cnot_h<2, 1, 0>(st); g_cnot_h<1, 0, 0>(st);
        g_rx_h<3, 0>(st, sCS[42 + 1]); g_rx_h<2, 0>(st, sCS[42 + 2]);
        g_rx_h<1, 0>(st, sCS[42 + 3]);
        store_half<TT1, 0>(sSt, pbT1, st);
        g_rx_h<3, 1>(st, sCS[28 + 1]); g_rx_h<2, 1>(st, sCS[28 + 2]);
        g_rx_h<1, 1>(st, sCS[28 + 3]); g_rx_h<0, 1>(st, sCS[28 + 4]);
        g_cnot_h<4, 3, 1>(st); g_cnot_h<3, 2, 1>(st); g_cnot_h<2, 1, 1>(st); g_cnot_h<1, 0, 1>(st);
        g_rx_h<3, 1>(st, sCS[42 + 1]); g_rx_h<2, 1>(st, sCS[42 + 2]);
        g_rx_h<1, 1>(st, sCS[42 + 3]);
        store_half<TT1, 1>(sSt, pbT1, st);
    }
    __syncthreads();

    // ===== P2: L1-T2 {q5..q9} (TT2Q), fold CNOT(q4,q5); L2 q4..q8 =====
    {
        cf2 c5 = sCS[28 + 5], c6 = sCS[28 + 6], c7 = sCS[28 + 7];
        cf2 c8 = sCS[28 + 8], c9 = sCS[28 + 9];
        cf2 e4 = sCS[42 + 4], e5 = sCS[42 + 5], e6 = sCS[42 + 6];
        cf2 e7 = sCS[42 + 7], e8 = sCS[42 + 8];
        load_tile_fold<TT2Q>(sSt, pbT2lo, pbT2hi, st);
        g_rx<4>(st, c5);                        // L1 q5 (cross l4)
        g_rx_lane_dpp<0xB1>(st, e4);            // L2 q4: lane^1 (t0=q4), after fold
        g_rx_h<3,0>(st, c6); g_rx_h<2,0>(st, c7); g_rx_h<1,0>(st, c8); g_rx_h<0,0>(st, c9);
        g_cnot_h<3,2,0>(st); g_cnot_h<2,1,0>(st); g_cnot_h<1,0,0>(st);
        g_rx_h<3,1>(st, c6); g_rx_h<2,1>(st, c7); g_rx_h<1,1>(st, c8); g_rx_h<0,1>(st, c9);
        g_cnot_h<4,3,1>(st); g_cnot_h<3,2,1>(st); g_cnot_h<2,1,1>(st); g_cnot_h<1,0,1>(st);
        g_rx<4>(st, e5);                        // L2 q5 (needs (q5,q6) from hi chain)
        g_rx_h<3,0>(st, e6); g_rx_h<2,0>(st, e7); g_rx_h<1,0>(st, e8);
        store_half<TT2Q, 0>(sSt, pbT2, st);
        g_rx_h<3,1>(st, e6); g_rx_h<2,1>(st, e7); g_rx_h<1,1>(st, e8);
        store_half<TT2Q, 1>(sSt, pbT2, st);
    }
    __syncthreads();

    // ===== P3: L1-T3 (finish ring) + L2 q9..q13,q0 + parity epilogue =====
    // TT3: l4..l0 = q10,q11,q12,q13,q0; t0=q9 t1=q8 t2=q7 t3=q6 t4=q5 t5=q4
    //      t6=q3 t7=q2 t8=q1
    {
        cf2 cA = sCS[28 + 10], cB = sCS[28 + 11], cC = sCS[28 + 12], cD = sCS[28 + 13];
        cf2 eA = sCS[42 + 10], eB = sCS[42 + 11], eC = sCS[42 + 12], eD = sCS[42 + 13];
        cf2 e9 = sCS[42 + 9],  e0 = sCS[42 + 0];
        load_tile_fold<TT3>(sSt, pbT3lo, pbT3hi, st);
        g_rx<4>(st, cA);                        // L1 q10 (cross l4)
        g_rx_lane_dpp<0xB1>(st, e9);            // L2 q9: lane^1 (t0=q9), after fold
        g_rx_h<3,0>(st, cB); g_rx_h<2,0>(st, cC); g_rx_h<1,0>(st, cD);
        g_cnot_h<3,2,0>(st); g_cnot_h<2,1,0>(st); g_cnot_h<1,0,0>(st);
        g_rx_h<3,1>(st, cB); g_rx_h<2,1>(st, cC); g_rx_h<1,1>(st, cD);
        g_cnot_h<4,3,1>(st); g_cnot_h<3,2,1>(st); g_cnot_h<2,1,1>(st); g_cnot_h<1,0,1>(st);
        // L1 ring complete. Remaining L2 rotations, all in-register:
        g_rx<4>(st, eA);                        // L2 q10
        g_rx_h<3,0>(st, eB); g_rx_h<2,0>(st, eC); g_rx_h<1,0>(st, eD); g_rx_h<0,0>(st, e0);
        g_rx_h<3,1>(st, eB); g_rx_h<2,1>(st, eC); g_rx_h<1,1>(st, eD); g_rx_h<0,1>(st, e0);
    }

    // ====== epilogue: L2 ring folded as prefix-parity signs ======
    // b-bits: b0=j0(q0) b13=j1 b12=j2 b11=j3 b10=j4; b9=t0 b8=t1 .. b1=t8.
    // (Mb)_k = b0^..^bk (k>=1), (Mb)_0 = b1^..^b13.
    // Amp sign classes: q1..q9 -> j0; q10 -> j0^j4; q11 -> j0^j4^j3;
    // q12 -> j0^j4^j3^j2; q13 -> j0^j4^j3^j2^j1; q0 -> j4^j3^j2^j1.
    // Thread parity T_k = W ^ L_k: W-part over wave bits (t6..t8), L-part
    // over lane bits (t0..t5). T1..T3 are wave-uniform -> share the plain
    // reduction of Aa; signs applied once at the lane-63 write.
    {
        float Aa = 0.f, Ab = 0.f, Ac = 0.f, Ad = 0.f, Ae = 0.f, Af = 0.f;
        sfor<TA>([&](auto jc) {
            constexpr int j = decltype(jc)::v;
            cf2 v = amp<j>(st);
            float pj = v.x * v.x + v.y * v.y;
            constexpr int j0 = j & 1, j1 = (j >> 1) & 1, j2 = (j >> 2) & 1,
                          j3 = (j >> 3) & 1, j4 = (j >> 4) & 1;
            constexpr int sa = j0;
            constexpr int sb = j0 ^ j4;
            constexpr int sc = sb ^ j3;
            constexpr int sd = sc ^ j2;
            constexpr int se = sd ^ j1;
            constexpr int sf = se ^ j0;   // j4^j3^j2^j1
            Aa += sa ? -pj : pj;
            Ab += sb ? -pj : pj;
            Ac += sc ? -pj : pj;
            Ad += sd ? -pj : pj;
            Ae += se ? -pj : pj;
            Af += sf ? -pj : pj;
        });
        // lane-suffix parities L4..L9 (lane bits t0..t5) and wave parities W1..W3
        const int t0 = tid & 1,        t1 = (tid >> 1) & 1, t2 = (tid >> 2) & 1,
                  t3 = (tid >> 3) & 1, t4 = (tid >> 4) & 1, t5 = (tid >> 5) & 1,
                  t6 = (tid >> 6) & 1, t7 = (tid >> 7) & 1, t8 = (tid >> 8) & 1;
        const int L4 = t5, L5 = L4 ^ t4, L6 = L5 ^ t3;
        const int L7 = L6 ^ t2, L8 = L7 ^ t1, L9 = L8 ^ t0;
        const int W1 = t8, W2 = W1 ^ t7, W3 = W2 ^ t6;

        // 12 DPP reductions (pure VALU; sum lands in lane 63)
        float R0 = wave_red(Aa);
        float R4 = wave_red(L4 ? -Aa : Aa);
        float R5 = wave_red(L5 ? -Aa : Aa);
        float R6 = wave_red(L6 ? -Aa : Aa);
        float R7 = wave_red(L7 ? -Aa : Aa);
        float R8 = wave_red(L8 ? -Aa : Aa);
        float R9 = wave_red(L9 ? -Aa : Aa);
        float RB = wave_red(L9 ? -Ab : Ab);
        float RC = wave_red(L9 ? -Ac : Ac);
        float RD = wave_red(L9 ? -Ad : Ad);
        float RE = wave_red(L9 ? -Ae : Ae);
        float RF = wave_red(L9 ? -Af : Af);

        const int wv = tid >> 6, ln = tid & 63;
        if (ln == 63) {
            sRed[wv][0]  = W3 ? -RF : RF;    // T9 = W3^L9
            sRed[wv][1]  = W1 ? -R0 : R0;    // T1
            sRed[wv][2]  = W2 ? -R0 : R0;    // T2
            sRed[wv][3]  = W3 ? -R0 : R0;    // T3
            sRed[wv][4]  = W3 ? -R4 : R4;    // T4 = W3^L4
            sRed[wv][5]  = W3 ? -R5 : R5;
            sRed[wv][6]  = W3 ? -R6 : R6;
            sRed[wv][7]  = W3 ? -R7 : R7;
            sRed[wv][8]  = W3 ? -R8 : R8;
            sRed[wv][9]  = W3 ? -R9 : R9;
            sRed[wv][10] = W3 ? -RB : RB;
            sRed[wv][11] = W3 ? -RC : RC;
            sRed[wv][12] = W3 ? -RD : RD;
            sRed[wv][13] = W3 ? -RE : RE;
        }
        __syncthreads();
        if (tid < NQ) {
            float acc = 0.f;
#pragma unroll
            for (int k = 0; k < NW; ++k) acc += sRed[k][tid];
            out[b * NQ + tid] = acc;
        }
    }
}

extern "C" void kernel_launch(void* const* d_in, const int* in_sizes, int n_in,
                              void* d_out, int out_size, void* d_ws, size_t ws_size,
                              hipStream_t stream) {
    const float* x = (const float*)d_in[0];   // (256, 14) float32
    const float* w = (const float*)d_in[1];   // (3, 14) float32
    float* out = (float*)d_out;               // (256, 14) float32
    qsim_kernel<<<256, NT, 0, stream>>>(x, w, out);
}